// Round 10
// baseline (206.011 us; speedup 1.0000x reference)
//
#include <hip/hip_runtime.h>
#include <hip/hip_bf16.h>
#include <math.h>

constexpr int CH = 256;       // input channels
constexpr int CC = 512;       // concat width
constexpr int AP = 16;        // padded alpha row stride (12 heads used)

typedef __bf16 bf16x8 __attribute__((ext_vector_type(8)));
typedef float  f32x4  __attribute__((ext_vector_type(4)));
typedef float  f32x2  __attribute__((ext_vector_type(2)));
typedef int    i32x2  __attribute__((ext_vector_type(2)));
typedef __attribute__((address_space(3))) void lds_void;
typedef __attribute__((address_space(1))) void glb_void;

__device__ inline unsigned short f2bf(float f) {
    union { float f; unsigned u; } v; v.f = f;
    unsigned r = v.u + 0x7FFFu + ((v.u >> 16) & 1u);
    return (unsigned short)(r >> 16);
}

// ---------------------------------------------------------------------------
// Fused pre-pass: LN(->bf16) + weight transpose/convert + Pt=(W·a)
// block ranges: [0,LNB) LN | +512 WT1 | +512 WTu | +32 Pt
// ---------------------------------------------------------------------------
__global__ void fused_pre_kernel(const float* __restrict__ x, const float* __restrict__ gamma,
                                 const float* __restrict__ beta,
                                 const float* __restrict__ W1, const float* __restrict__ W2,
                                 const float* __restrict__ Wu,
                                 const float* __restrict__ as1, const float* __restrict__ ad1,
                                 const float* __restrict__ as2, const float* __restrict__ ad2,
                                 unsigned short* __restrict__ xnb,
                                 unsigned short* __restrict__ WT1, unsigned short* __restrict__ WTu,
                                 unsigned short* __restrict__ Pt,
                                 int N, int LNB) {
    int b = blockIdx.x;
    int t = threadIdx.x;
    if (b < LNB) {
        int wid = b * 4 + (t >> 6);
        int lane = t & 63;
        if (wid >= N) return;
        const float4 v = *(const float4*)(x + (size_t)wid * CH + lane * 4);
        float s = v.x + v.y + v.z + v.w;
        float sq = v.x * v.x + v.y * v.y + v.z * v.z + v.w * v.w;
        #pragma unroll
        for (int o = 32; o; o >>= 1) { s += __shfl_xor(s, o); sq += __shfl_xor(sq, o); }
        float mu = s * (1.0f / CH);
        float var = sq * (1.0f / CH) - mu * mu;
        float rs = rsqrtf(var + 1e-5f);
        float4 g = *(const float4*)(gamma + lane * 4);
        float4 bb = *(const float4*)(beta + lane * 4);
        unsigned short o0 = f2bf((v.x - mu) * rs * g.x + bb.x);
        unsigned short o1 = f2bf((v.y - mu) * rs * g.y + bb.y);
        unsigned short o2 = f2bf((v.z - mu) * rs * g.z + bb.z);
        unsigned short o3 = f2bf((v.w - mu) * rs * g.w + bb.w);
        uint2 pk;
        pk.x = (unsigned)o0 | ((unsigned)o1 << 16);
        pk.y = (unsigned)o2 | ((unsigned)o3 << 16);
        *(uint2*)(xnb + (size_t)wid * CH + lane * 4) = pk;
    } else if (b < LNB + 512) {
        int idx = (b - LNB) * 256 + t;              // 512*256
        int n = idx >> 8, k = idx & 255;
        float v = (n < 256) ? W1[(size_t)k * 256 + n] : W2[(size_t)k * 256 + (n - 256)];
        WT1[idx] = f2bf(v);
    } else if (b < LNB + 1024) {
        int idx = (b - LNB - 512) * 256 + t;        // 256*512
        int n = idx >> 9, k = idx & 511;
        WTu[idx] = f2bf(Wu[(size_t)k * 256 + n]);
    } else {
        // Pt[32][256]: row n = α-projection col; cols 0..11 src, 16..27 dst
        int n = b - LNB - 1024;                     // 0..31
        int k = t;                                  // 0..255
        float a = 0.f;
        if (n < 4) {
            for (int c = 0; c < 64; ++c) a += W1[(size_t)k * 256 + n * 64 + c] * as1[n * 64 + c];
        } else if (n < 12) {
            for (int c = 0; c < 32; ++c) a += W2[(size_t)k * 256 + (n - 4) * 32 + c] * as2[(n - 4) * 32 + c];
        } else if (n >= 16 && n < 20) {
            for (int c = 0; c < 64; ++c) a += W1[(size_t)k * 256 + (n - 16) * 64 + c] * ad1[(n - 16) * 64 + c];
        } else if (n >= 20 && n < 28) {
            for (int c = 0; c < 32; ++c) a += W2[(size_t)k * 256 + (n - 20) * 32 + c] * ad2[(n - 20) * 32 + c];
        }
        Pt[n * 256 + k] = f2bf(a);
    }
}

// ---------------------------------------------------------------------------
// bf16 MFMA GEMM core, 128x128 tile, BK=32, 4 waves, double-buffered LDS.
// ---------------------------------------------------------------------------
template<int K>
__device__ inline void gemm_core32(const unsigned short* __restrict__ Ab,
                                   const unsigned short* __restrict__ Bt,
                                   unsigned short* As, unsigned short* Bs,   // each [2][128*32]
                                   f32x4 acc[4][4], int m0, int n0, int M) {
    const int t = threadIdx.x;
    const int lane = t & 63;
    const int wave = t >> 6;
    const int wr = wave >> 1, wc = wave & 1;
    const int rowc = lane >> 2;                        // row within 16-row chunk
    const int eslot = lane & 3;                        // 16B slot within 64B row
    const int fr = lane & 15;
    const int fkb = (lane >> 4) << 4;                  // logical colbyte

    auto stage = [&](int buf, int k0) {
        #pragma unroll
        for (int c = 0; c < 2; ++c) {
            int chunk = wave * 2 + c;                  // 0..7 (16 rows each)
            int row = chunk * 16 + rowc;               // 0..127
            int se = ((eslot ^ (row & 3)) << 3);       // inverse-swizzled elem col
            int gra = m0 + row; if (gra >= M) gra = M - 1;
            __builtin_amdgcn_global_load_lds((const glb_void*)(Ab + (size_t)gra * K + k0 + se),
                                             (lds_void*)&As[buf * 4096 + chunk * 512], 16, 0, 0);
            __builtin_amdgcn_global_load_lds((const glb_void*)(Bt + (size_t)(n0 + row) * K + k0 + se),
                                             (lds_void*)&Bs[buf * 4096 + chunk * 512], 16, 0, 0);
        }
    };
    auto compute = [&](int buf) {
        const int bb = buf * 8192;                     // byte offset
        bf16x8 af[4], bfr[4];
        #pragma unroll
        for (int m = 0; m < 4; ++m) {
            int r = wr * 64 + m * 16 + fr;
            int pc = fkb ^ ((r & 3) << 4);
            af[m] = *(const bf16x8*)((const char*)As + bb + r * 64 + pc);
        }
        #pragma unroll
        for (int n = 0; n < 4; ++n) {
            int r = wc * 64 + n * 16 + fr;
            int pc = fkb ^ ((r & 3) << 4);
            bfr[n] = *(const bf16x8*)((const char*)Bs + bb + r * 64 + pc);
        }
        #pragma unroll
        for (int m = 0; m < 4; ++m)
            #pragma unroll
            for (int n = 0; n < 4; ++n)
                acc[m][n] = __builtin_amdgcn_mfma_f32_16x16x32_bf16(af[m], bfr[n], acc[m][n], 0, 0, 0);
    };

    stage(0, 0);
    __syncthreads();
    int cur = 0;
    #pragma unroll
    for (int k0 = 32; k0 < K; k0 += 32) {
        stage(cur ^ 1, k0);     // issue next-tile loads
        compute(cur);           // MFMA on current tile
        __syncthreads();
        cur ^= 1;
    }
    compute(cur);
}

// GEMM1 grid: [0,G1B) main h-GEMM | [G1B,G1B+MB) alpha panel | rest histogram
__global__ __launch_bounds__(256) void gemm1_mfma(
    const unsigned short* __restrict__ Ab, const unsigned short* __restrict__ Bt,
    const unsigned short* __restrict__ Pt,
    unsigned char* __restrict__ Hq,
    float* __restrict__ alpha_src, float* __restrict__ alpha_dst, int M, int MB, int G1B,
    const int* __restrict__ dstE, int* __restrict__ deg, int E) {
    __shared__ unsigned short As[8192];                // 2 bufs x 128x32
    __shared__ unsigned short Bs[8192];                // main: 2 bufs; alpha: Pt[32][256]
    const int s = blockIdx.x;
    if (s >= G1B + MB) {                               // fused histogram blocks
        int i = (s - G1B - MB) * 256 + threadIdx.x;
        if (i < E) atomicAdd(&deg[dstE[i]], 1);
        return;
    }
    const int lane = threadIdx.x & 63;
    const int wave = threadIdx.x >> 6;
    const int fr = lane & 15;
    const int fkb = (lane >> 4) << 4;
    const int orow = (lane >> 4) * 4;

    if (s < G1B) {
        const int xcd = s & 7;
        const int jj = s >> 3;
        const int n_blk = jj & 3;                      // NB=4
        const int m_blk = (jj >> 2) * 8 + xcd;
        if (m_blk >= MB) return;
        const int m0 = m_blk * 128, n0 = n_blk * 128;
        const int wr = wave >> 1, wc = wave & 1;
        f32x4 acc[4][4] = {};
        gemm_core32<256>(Ab, Bt, As, Bs, acc, m0, n0, M);
        // fp8 e4m3 store
        #pragma unroll
        for (int m = 0; m < 4; ++m)
            #pragma unroll
            for (int j = 0; j < 4; ++j) {
                int r = m0 + wr * 64 + m * 16 + orow + j;
                if (r < M) {
                    #pragma unroll
                    for (int n = 0; n < 4; ++n) {
                        int ccol = n0 + wc * 64 + n * 16 + fr;
                        unsigned q = (unsigned)__builtin_amdgcn_cvt_pk_fp8_f32(
                            acc[m][n][j], acc[m][n][j], 0, false) & 0xffu;
                        Hq[(size_t)r * CC + ccol] = (unsigned char)q;
                    }
                }
            }
        return;
    }
    // ---- alpha panel block: 128 rows x 32 cols, K=256, Pt resident in LDS ----
    const int m_blk = s - G1B;
    if (m_blk >= MB) return;
    const int m0 = m_blk * 128;
    {
        int rr_in = lane >> 5;                         // 0..1
        int e32 = lane & 31;                           // 16B slot within 512B row
        #pragma unroll
        for (int c = 0; c < 4; ++c) {
            int chunk = wave * 4 + c;                  // 0..15
            int rr = chunk * 2 + rr_in;                // 0..31
            const unsigned short* g = Pt + rr * 256 + ((e32 ^ (rr & 7)) << 3);
            __builtin_amdgcn_global_load_lds((const glb_void*)g,
                                             (lds_void*)&Bs[chunk * 512], 16, 0, 0);
        }
    }
    const int rowc = lane >> 2, eslot = lane & 3;
    auto stageA = [&](int buf, int k0) {
        #pragma unroll
        for (int c = 0; c < 2; ++c) {
            int chunk = wave * 2 + c;
            int row = chunk * 16 + rowc;
            int gra = m0 + row; if (gra >= M) gra = M - 1;
            const unsigned short* g = Ab + (size_t)gra * 256 + k0 + ((eslot ^ (row & 3)) << 3);
            __builtin_amdgcn_global_load_lds((const glb_void*)g,
                                             (lds_void*)&As[buf * 4096 + chunk * 512], 16, 0, 0);
        }
    };
    f32x4 a2[2][2] = {};
    auto computeA = [&](int buf, int k0) {
        const int bb = buf * 8192;
        bf16x8 af[2], bf_[2];
        #pragma unroll
        for (int m = 0; m < 2; ++m) {
            int r = wave * 32 + m * 16 + fr;
            int pc = fkb ^ ((r & 3) << 4);
            af[m] = *(const bf16x8*)((const char*)As + bb + r * 64 + pc);
        }
        #pragma unroll
        for (int n = 0; n < 2; ++n) {
            int rb = n * 16 + fr;                      // Pt row 0..31
            int pcb = (k0 * 2 + fkb) ^ ((rb & 7) << 4);
            bf_[n] = *(const bf16x8*)((const char*)Bs + rb * 512 + pcb);
        }
        #pragma unroll
        for (int m = 0; m < 2; ++m)
            #pragma unroll
            for (int n = 0; n < 2; ++n)
                a2[m][n] = __builtin_amdgcn_mfma_f32_16x16x32_bf16(af[m], bf_[n], a2[m][n], 0, 0, 0);
    };
    stageA(0, 0);
    __syncthreads();
    int cur = 0;
    #pragma unroll
    for (int k0 = 32; k0 < 256; k0 += 32) {
        stageA(cur ^ 1, k0);
        computeA(cur, k0 - 32);
        __syncthreads();
        cur ^= 1;
    }
    computeA(cur, 224);
    #pragma unroll
    for (int m = 0; m < 2; ++m)
        #pragma unroll
        for (int j = 0; j < 4; ++j) {
            int r = m0 + wave * 32 + m * 16 + orow + j;
            if (fr < 12 && r < M) {
                alpha_src[(size_t)r * AP + fr] = a2[m][0][j];
                alpha_dst[(size_t)r * AP + fr] = a2[m][1][j];
            }
        }
}

// GEMM2: out(f32)[M,256] = x + xcat(bf16) @ WTu^T + bu  (nt residual/out)
__global__ __launch_bounds__(256) void gemm2_mfma(const unsigned short* __restrict__ Ab,
                                                  const unsigned short* __restrict__ Bt,
                                                  const float* __restrict__ bu,
                                                  const float* __restrict__ xres,
                                                  float* __restrict__ C, int M, int MB) {
    __shared__ unsigned short As[8192];
    __shared__ unsigned short Bs[8192];
    const int s = blockIdx.x;
    const int xcd = s & 7;
    const int jj = s >> 3;
    const int n_blk = jj & 1;                          // NB=2
    const int m_blk = (jj >> 1) * 8 + xcd;
    if (m_blk >= MB) return;
    const int m0 = m_blk * 128, n0 = n_blk * 128;
    const int lane = threadIdx.x & 63;
    const int wave = threadIdx.x >> 6;
    const int wr = wave >> 1, wc = wave & 1;
    f32x4 acc[4][4] = {};
    gemm_core32<512>(Ab, Bt, As, Bs, acc, m0, n0, M);
    const int fr = lane & 15;
    const int orow = (lane >> 4) * 4;
    #pragma unroll
    for (int m = 0; m < 4; ++m)
        #pragma unroll
        for (int j = 0; j < 4; ++j) {
            int r = m0 + wr * 64 + m * 16 + orow + j;
            if (r < M) {
                #pragma unroll
                for (int n = 0; n < 4; ++n) {
                    int ccol = n0 + wc * 64 + n * 16 + fr;
                    float xr = __builtin_nontemporal_load(&xres[(size_t)r * CH + ccol]);
                    __builtin_nontemporal_store(acc[m][n][j] + bu[ccol] + xr,
                                                &C[(size_t)r * CH + ccol]);
                }
            }
        }
}

// ---------------------------------------------------------------------------
// CSR build (scan adds +1 self-loop per node; deg holds in-degree only)
// ---------------------------------------------------------------------------
__global__ __launch_bounds__(256) void scan1_kernel(const int* __restrict__ deg, int* __restrict__ pre,
                                                    int* __restrict__ bsum, int n) {
    __shared__ int wsum[4];
    int t = threadIdx.x, lane = t & 63, w = t >> 6;
    int base = blockIdx.x * 1024 + t * 4;
    int v0 = base     < n ? deg[base]     + 1 : 0;
    int v1 = base + 1 < n ? deg[base + 1] + 1 : 0;
    int v2 = base + 2 < n ? deg[base + 2] + 1 : 0;
    int v3 = base + 3 < n ? deg[base + 3] + 1 : 0;
    int s = v0 + v1 + v2 + v3;
    int sc = s;
    #pragma unroll
    for (int o = 1; o < 64; o <<= 1) { int xx = __shfl_up(sc, o); if (lane >= o) sc += xx; }
    if (lane == 63) wsum[w] = sc;
    __syncthreads();
    int wo = 0;
    #pragma unroll
    for (int k = 0; k < 4; ++k) if (k < w) wo += wsum[k];
    int p = wo + sc - s;
    if (base     < n) pre[base]     = p; p += v0;
    if (base + 1 < n) pre[base + 1] = p; p += v1;
    if (base + 2 < n) pre[base + 2] = p; p += v2;
    if (base + 3 < n) pre[base + 3] = p;
    if (t == 255) bsum[blockIdx.x] = wo + sc;
}
__global__ void scan2_kernel(int* __restrict__ bsum, int nb) {
    int lane = threadIdx.x;
    int v = lane < nb ? bsum[lane] : 0;
    int sc = v;
    #pragma unroll
    for (int o = 1; o < 64; o <<= 1) { int xx = __shfl_up(sc, o); if (lane >= o) sc += xx; }
    if (lane < nb) bsum[lane] = sc - v;
}
__global__ void scan3_csr_kernel(const int* __restrict__ pre, const int* __restrict__ bsum,
                                 int* __restrict__ offsets, int* __restrict__ cursor,
                                 int* __restrict__ csr, int n, int total) {
    int i = blockIdx.x * 256 + threadIdx.x;
    if (i < n) {
        int off = pre[i] + bsum[i >> 10];
        offsets[i] = off;
        cursor[i] = off + 1;
        csr[off] = i;                                  // self-loop slot 0
    }
    if (i == 0) offsets[n] = total;
}
__global__ void scatter_kernel(const int* __restrict__ src, const int* __restrict__ dst,
                               int* __restrict__ cursor, int* __restrict__ csr, int E) {
    int i = blockIdx.x * blockDim.x + threadIdx.x;
    if (i < E) {
        int pos = atomicAdd(&cursor[dst[i]], 1);
        csr[pos] = src[i];
    }
}

// ---------------------------------------------------------------------------
// Aggregation: TWO waves per node (4 fp8 channels/lane), single edge pass,
// post-normalized softmax, scalarized control stream, packed f32x2 accum.
// ---------------------------------------------------------------------------
__global__ void aggregate_kernel(const unsigned char* __restrict__ Hq,
                                 const float* __restrict__ alpha_src,
                                 const float* __restrict__ alpha_dst,
                                 const int* __restrict__ offsets,
                                 const int* __restrict__ csr,
                                 const float* __restrict__ b1, const float* __restrict__ b2,
                                 unsigned short* __restrict__ xcb, int N) {
    int t = threadIdx.x;
    int n = __builtin_amdgcn_readfirstlane((int)(blockIdx.x * 2 + (t >> 7)));
    if (n >= N) return;
    int lane = t & 63;
    int half = (t >> 6) & 1;
    int c0 = half * 256 + lane * 4;                    // 4 channels per lane
    int hid = (c0 < 256) ? (c0 >> 6) : (4 + ((c0 - 256) >> 5));
    int beg = offsets[n], end = offsets[n + 1];
    float adh = alpha_dst[(size_t)n * AP + hid];

    float ssum = 0.f;
    f32x2 A0 = {0.f, 0.f}, A1 = {0.f, 0.f};

    int i = beg;
    for (; i + 4 <= end; i += 4) {
        int ss[4];
        #pragma unroll
        for (int u = 0; u < 4; ++u) ss[u] = csr[i + u];          // scalar loads (uniform addr)
        float lw[4];
        #pragma unroll
        for (int u = 0; u < 4; ++u) lw[u] = alpha_src[(size_t)ss[u] * AP + hid];
        unsigned hv[4];
        #pragma unroll
        for (int u = 0; u < 4; ++u) hv[u] = *(const unsigned*)(Hq + (size_t)ss[u] * CC + c0);
        #pragma unroll
        for (int u = 0; u < 4; ++u) {
            float l = lw[u] + adh;
            l = fmaxf(l, 0.2f * l);                              // leaky relu
            float wv = __expf(l);
            ssum += wv;
            f32x2 wv2; wv2[0] = wv; wv2[1] = wv;
            A0 += __builtin_amdgcn_cvt_pk_f32_fp8(hv[u], false) * wv2;
            A1 += __builtin_amdgcn_cvt_pk_f32_fp8(hv[u], true)  * wv2;
        }
    }
    for (; i < end; ++i) {
        int s0 = csr[i];
        float l = alpha_src[(size_t)s0 * AP + hid] + adh;
        unsigned hv0 = *(const unsigned*)(Hq + (size_t)s0 * CC + c0);
        l = fmaxf(l, 0.2f * l);
        float wv = __expf(l);
        ssum += wv;
        f32x2 wv2; wv2[0] = wv; wv2[1] = wv;
        A0 += __builtin_amdgcn_cvt_pk_f32_fp8(hv0, false) * wv2;
        A1 += __builtin_amdgcn_cvt_pk_f32_fp8(hv0, true)  * wv2;
    }

    float inv = 1.0f / (ssum + 1e-16f);
    const float* bb = (c0 < 256) ? (b1 + c0) : (b2 + (c0 - 256));
    float4 bb4 = *(const float4*)(bb);
    float o[4];
    o[0] = A0[0] * inv + bb4.x; o[1] = A0[1] * inv + bb4.y;
    o[2] = A1[0] * inv + bb4.z; o[3] = A1[1] * inv + bb4.w;
    #pragma unroll
    for (int j = 0; j < 4; ++j) o[j] = o[j] > 0.f ? o[j] : expm1f(o[j]);
    unsigned short u[4];
    #pragma unroll
    for (int j = 0; j < 4; ++j) u[j] = f2bf(o[j]);
    i32x2 pk;
    pk[0] = (int)((unsigned)u[0] | ((unsigned)u[1] << 16));
    pk[1] = (int)((unsigned)u[2] | ((unsigned)u[3] << 16));
    __builtin_nontemporal_store(pk, (i32x2*)(xcb + (size_t)n * CC + c0));
}

// ---------------------------------------------------------------------------
// Launch
// ---------------------------------------------------------------------------
extern "C" void kernel_launch(void* const* d_in, const int* in_sizes, int n_in,
                              void* d_out, int out_size, void* d_ws, size_t ws_size,
                              hipStream_t stream) {
    const float* x     = (const float*)d_in[0];
    const int*   ei    = (const int*)d_in[1];
    const float* gamma = (const float*)d_in[2];
    const float* beta  = (const float*)d_in[3];
    const float* W1    = (const float*)d_in[4];
    const float* as1   = (const float*)d_in[5];
    const float* ad1   = (const float*)d_in[6];
    const float* b1    = (const float*)d_in[7];
    const float* W2    = (const float*)d_in[8];
    const float* as2   = (const float*)d_in[9];
    const float* ad2   = (const float*)d_in[10];
    const float* b2    = (const float*)d_in[11];
    const float* Wu    = (const float*)d_in[12];
    const float* bu    = (const float*)d_in[13];
    float* out = (float*)d_out;

    const int N = in_sizes[0] / CH;
    const int E = in_sizes[1] / 2;
    const int* src = ei;
    const int* dst = ei + E;

    char* w = (char*)d_ws;
    auto alloc = [&](size_t bytes) { char* p = w; w += (bytes + 255) & ~(size_t)255; return p; };
    unsigned char*  Hq  = (unsigned char*)alloc((size_t)N * CC);
    unsigned short* xnb = (unsigned short*)alloc((size_t)N * CH * 2);
    unsigned short* xcb = (unsigned short*)alloc((size_t)N * CC * 2);
    unsigned short* WT1 = (unsigned short*)alloc(512 * 256 * 2);
    unsigned short* WTu = (unsigned short*)alloc(256 * 512 * 2);
    unsigned short* Pt  = (unsigned short*)alloc(32 * 256 * 2);
    float* alpha_src = (float*)alloc((size_t)N * AP * 4);
    float* alpha_dst = (float*)alloc((size_t)N * AP * 4);
    int* deg     = (int*)alloc((size_t)N * 4);
    int* pre     = (int*)alloc((size_t)N * 4);
    int* bsum    = (int*)alloc(64 * 4);
    int* offsets = (int*)alloc(((size_t)N + 1) * 4);
    int* cursor  = (int*)alloc((size_t)N * 4);
    int* csr     = (int*)alloc(((size_t)E + N) * 4);

    hipMemsetAsync(deg, 0, (size_t)N * 4, stream);

    const int LNB = (N + 3) / 4;
    fused_pre_kernel<<<LNB + 1056, 256, 0, stream>>>(
        x, gamma, beta, W1, W2, Wu, as1, ad1, as2, ad2,
        xnb, WT1, WTu, Pt, N, LNB);

    const int MB = (N + 127) / 128;
    const int MB8 = ((MB + 7) / 8) * 8;
    const int G1B = MB8 * 4;
    const int HB = (E + 255) / 256;
    gemm1_mfma<<<G1B + MB + HB, 256, 0, stream>>>(xnb, WT1, Pt, Hq, alpha_src, alpha_dst,
                                                  N, MB, G1B, dst, deg, E);

    int nb = (N + 1023) / 1024;
    scan1_kernel<<<nb, 256, 0, stream>>>(deg, pre, bsum, N);
    scan2_kernel<<<1, 64, 0, stream>>>(bsum, nb);
    scan3_csr_kernel<<<(N + 255) / 256, 256, 0, stream>>>(pre, bsum, offsets, cursor, csr, N, E + N);
    scatter_kernel<<<(E + 255) / 256, 256, 0, stream>>>(src, dst, cursor, csr, E);

    aggregate_kernel<<<(N + 1) / 2, 256, 0, stream>>>(Hq, alpha_src, alpha_dst, offsets, csr,
                                                      b1, b2, xcb, N);

    gemm2_mfma<<<MB8 * 2, 256, 0, stream>>>(xcb, WTu, bu, x, out, N, MB);
}

// Round 11
// 194.281 us; speedup vs baseline: 1.0604x; 1.0604x over previous
//
#include <hip/hip_runtime.h>
#include <hip/hip_bf16.h>
#include <math.h>

constexpr int CH = 256;       // input channels
constexpr int CC = 512;       // concat width
constexpr int AP = 16;        // padded alpha row stride (12 heads used)

typedef __bf16 bf16x8 __attribute__((ext_vector_type(8)));
typedef float  f32x4  __attribute__((ext_vector_type(4)));
typedef float  f32x2  __attribute__((ext_vector_type(2)));
typedef int    i32x4  __attribute__((ext_vector_type(4)));
typedef __attribute__((address_space(3))) void lds_void;
typedef __attribute__((address_space(1))) void glb_void;

__device__ inline unsigned short f2bf(float f) {
    union { float f; unsigned u; } v; v.f = f;
    unsigned r = v.u + 0x7FFFu + ((v.u >> 16) & 1u);
    return (unsigned short)(r >> 16);
}

// ---------------------------------------------------------------------------
// Fused pre-pass: LN(->bf16) + weight transpose/convert + Pt=(W·a) + deg zero
// block ranges: [0,LNB) LN | +512 WT1 | +512 WTu | +32 Pt | +DEGZ deg=0
// ---------------------------------------------------------------------------
__global__ void fused_pre_kernel(const float* __restrict__ x, const float* __restrict__ gamma,
                                 const float* __restrict__ beta,
                                 const float* __restrict__ W1, const float* __restrict__ W2,
                                 const float* __restrict__ Wu,
                                 const float* __restrict__ as1, const float* __restrict__ ad1,
                                 const float* __restrict__ as2, const float* __restrict__ ad2,
                                 unsigned short* __restrict__ xnb,
                                 unsigned short* __restrict__ WT1, unsigned short* __restrict__ WTu,
                                 unsigned short* __restrict__ Pt,
                                 int* __restrict__ deg,
                                 int N, int LNB) {
    int b = blockIdx.x;
    int t = threadIdx.x;
    if (b < LNB) {
        int wid = b * 4 + (t >> 6);
        int lane = t & 63;
        if (wid >= N) return;
        const float4 v = *(const float4*)(x + (size_t)wid * CH + lane * 4);
        float s = v.x + v.y + v.z + v.w;
        float sq = v.x * v.x + v.y * v.y + v.z * v.z + v.w * v.w;
        #pragma unroll
        for (int o = 32; o; o >>= 1) { s += __shfl_xor(s, o); sq += __shfl_xor(sq, o); }
        float mu = s * (1.0f / CH);
        float var = sq * (1.0f / CH) - mu * mu;
        float rs = rsqrtf(var + 1e-5f);
        float4 g = *(const float4*)(gamma + lane * 4);
        float4 bb = *(const float4*)(beta + lane * 4);
        unsigned short o0 = f2bf((v.x - mu) * rs * g.x + bb.x);
        unsigned short o1 = f2bf((v.y - mu) * rs * g.y + bb.y);
        unsigned short o2 = f2bf((v.z - mu) * rs * g.z + bb.z);
        unsigned short o3 = f2bf((v.w - mu) * rs * g.w + bb.w);
        uint2 pk;
        pk.x = (unsigned)o0 | ((unsigned)o1 << 16);
        pk.y = (unsigned)o2 | ((unsigned)o3 << 16);
        *(uint2*)(xnb + (size_t)wid * CH + lane * 4) = pk;
    } else if (b < LNB + 512) {
        int idx = (b - LNB) * 256 + t;              // 512*256
        int n = idx >> 8, k = idx & 255;
        float v = (n < 256) ? W1[(size_t)k * 256 + n] : W2[(size_t)k * 256 + (n - 256)];
        WT1[idx] = f2bf(v);
    } else if (b < LNB + 1024) {
        int idx = (b - LNB - 512) * 256 + t;        // 256*512
        int n = idx >> 9, k = idx & 511;
        WTu[idx] = f2bf(Wu[(size_t)k * 256 + n]);
    } else if (b < LNB + 1056) {
        // Pt[32][256]: row n = α-projection col; cols 0..11 src, 16..27 dst
        int n = b - LNB - 1024;                     // 0..31
        int k = t;                                  // 0..255
        float a = 0.f;
        if (n < 4) {
            for (int c = 0; c < 64; ++c) a += W1[(size_t)k * 256 + n * 64 + c] * as1[n * 64 + c];
        } else if (n < 12) {
            for (int c = 0; c < 32; ++c) a += W2[(size_t)k * 256 + (n - 4) * 32 + c] * as2[(n - 4) * 32 + c];
        } else if (n >= 16 && n < 20) {
            for (int c = 0; c < 64; ++c) a += W1[(size_t)k * 256 + (n - 16) * 64 + c] * ad1[(n - 16) * 64 + c];
        } else if (n >= 20 && n < 28) {
            for (int c = 0; c < 32; ++c) a += W2[(size_t)k * 256 + (n - 20) * 32 + c] * ad2[(n - 20) * 32 + c];
        }
        Pt[n * 256 + k] = f2bf(a);
    } else {
        int i = (b - LNB - 1056) * 256 + t;
        if (i < N) deg[i] = 0;                      // zero for histogram
    }
}

// ---------------------------------------------------------------------------
// bf16 MFMA GEMM core, 128x128 tile, BK=32, 4 waves, double-buffered LDS.
// ---------------------------------------------------------------------------
template<int K>
__device__ inline void gemm_core32(const unsigned short* __restrict__ Ab,
                                   const unsigned short* __restrict__ Bt,
                                   unsigned short* As, unsigned short* Bs,   // each [2][128*32]
                                   f32x4 acc[4][4], int m0, int n0, int M) {
    const int t = threadIdx.x;
    const int lane = t & 63;
    const int wave = t >> 6;
    const int wr = wave >> 1, wc = wave & 1;
    const int rowc = lane >> 2;                        // row within 16-row chunk
    const int eslot = lane & 3;                        // 16B slot within 64B row
    const int fr = lane & 15;
    const int fkb = (lane >> 4) << 4;                  // logical colbyte

    auto stage = [&](int buf, int k0) {
        #pragma unroll
        for (int c = 0; c < 2; ++c) {
            int chunk = wave * 2 + c;                  // 0..7 (16 rows each)
            int row = chunk * 16 + rowc;               // 0..127
            int se = ((eslot ^ (row & 3)) << 3);       // inverse-swizzled elem col
            int gra = m0 + row; if (gra >= M) gra = M - 1;
            __builtin_amdgcn_global_load_lds((const glb_void*)(Ab + (size_t)gra * K + k0 + se),
                                             (lds_void*)&As[buf * 4096 + chunk * 512], 16, 0, 0);
            __builtin_amdgcn_global_load_lds((const glb_void*)(Bt + (size_t)(n0 + row) * K + k0 + se),
                                             (lds_void*)&Bs[buf * 4096 + chunk * 512], 16, 0, 0);
        }
    };
    auto compute = [&](int buf) {
        const int bb = buf * 8192;                     // byte offset
        bf16x8 af[4], bfr[4];
        #pragma unroll
        for (int m = 0; m < 4; ++m) {
            int r = wr * 64 + m * 16 + fr;
            int pc = fkb ^ ((r & 3) << 4);
            af[m] = *(const bf16x8*)((const char*)As + bb + r * 64 + pc);
        }
        #pragma unroll
        for (int n = 0; n < 4; ++n) {
            int r = wc * 64 + n * 16 + fr;
            int pc = fkb ^ ((r & 3) << 4);
            bfr[n] = *(const bf16x8*)((const char*)Bs + bb + r * 64 + pc);
        }
        #pragma unroll
        for (int m = 0; m < 4; ++m)
            #pragma unroll
            for (int n = 0; n < 4; ++n)
                acc[m][n] = __builtin_amdgcn_mfma_f32_16x16x32_bf16(af[m], bfr[n], acc[m][n], 0, 0, 0);
    };

    stage(0, 0);
    __syncthreads();
    int cur = 0;
    #pragma unroll
    for (int k0 = 32; k0 < K; k0 += 32) {
        stage(cur ^ 1, k0);     // issue next-tile loads
        compute(cur);           // MFMA on current tile
        __syncthreads();
        cur ^= 1;
    }
    compute(cur);
}

// GEMM1 grid: [0,G1B) main h-GEMM | [G1B,G1B+MB) alpha panel | rest histogram
__global__ __launch_bounds__(256) void gemm1_mfma(
    const unsigned short* __restrict__ Ab, const unsigned short* __restrict__ Bt,
    const unsigned short* __restrict__ Pt,
    unsigned char* __restrict__ Hq,
    float* __restrict__ alpha_src, float* __restrict__ alpha_dst, int M, int MB, int G1B,
    const int* __restrict__ dstE, int* __restrict__ deg, int E) {
    __shared__ unsigned short As[8192];                // 2 bufs x 128x32
    __shared__ unsigned short Bs[8192];                // main: 2 bufs; alpha: Pt[32][256]
    const int s = blockIdx.x;
    if (s >= G1B + MB) {                               // fused histogram blocks
        int i = (s - G1B - MB) * 256 + threadIdx.x;
        if (i < E) atomicAdd(&deg[dstE[i]], 1);
        return;
    }
    const int lane = threadIdx.x & 63;
    const int wave = threadIdx.x >> 6;
    const int fr = lane & 15;
    const int fkb = (lane >> 4) << 4;
    const int orow = (lane >> 4) * 4;

    if (s < G1B) {
        const int xcd = s & 7;
        const int jj = s >> 3;
        const int n_blk = jj & 3;                      // NB=4
        const int m_blk = (jj >> 2) * 8 + xcd;
        if (m_blk >= MB) return;
        const int m0 = m_blk * 128, n0 = n_blk * 128;
        const int wr = wave >> 1, wc = wave & 1;
        f32x4 acc[4][4] = {};
        gemm_core32<256>(Ab, Bt, As, Bs, acc, m0, n0, M);
        // fp8 e4m3 store
        #pragma unroll
        for (int m = 0; m < 4; ++m)
            #pragma unroll
            for (int j = 0; j < 4; ++j) {
                int r = m0 + wr * 64 + m * 16 + orow + j;
                if (r < M) {
                    #pragma unroll
                    for (int n = 0; n < 4; ++n) {
                        int ccol = n0 + wc * 64 + n * 16 + fr;
                        unsigned q = (unsigned)__builtin_amdgcn_cvt_pk_fp8_f32(
                            acc[m][n][j], acc[m][n][j], 0, false) & 0xffu;
                        Hq[(size_t)r * CC + ccol] = (unsigned char)q;
                    }
                }
            }
        return;
    }
    // ---- alpha panel block: 128 rows x 32 cols, K=256, Pt resident in LDS ----
    const int m_blk = s - G1B;
    if (m_blk >= MB) return;
    const int m0 = m_blk * 128;
    {
        int rr_in = lane >> 5;                         // 0..1
        int e32 = lane & 31;                           // 16B slot within 512B row
        #pragma unroll
        for (int c = 0; c < 4; ++c) {
            int chunk = wave * 4 + c;                  // 0..15
            int rr = chunk * 2 + rr_in;                // 0..31
            const unsigned short* g = Pt + rr * 256 + ((e32 ^ (rr & 7)) << 3);
            __builtin_amdgcn_global_load_lds((const glb_void*)g,
                                             (lds_void*)&Bs[chunk * 512], 16, 0, 0);
        }
    }
    const int rowc = lane >> 2, eslot = lane & 3;
    auto stageA = [&](int buf, int k0) {
        #pragma unroll
        for (int c = 0; c < 2; ++c) {
            int chunk = wave * 2 + c;
            int row = chunk * 16 + rowc;
            int gra = m0 + row; if (gra >= M) gra = M - 1;
            const unsigned short* g = Ab + (size_t)gra * 256 + k0 + ((eslot ^ (row & 3)) << 3);
            __builtin_amdgcn_global_load_lds((const glb_void*)g,
                                             (lds_void*)&As[buf * 4096 + chunk * 512], 16, 0, 0);
        }
    };
    f32x4 a2[2][2] = {};
    auto computeA = [&](int buf, int k0) {
        const int bb = buf * 8192;
        bf16x8 af[2], bf_[2];
        #pragma unroll
        for (int m = 0; m < 2; ++m) {
            int r = wave * 32 + m * 16 + fr;
            int pc = fkb ^ ((r & 3) << 4);
            af[m] = *(const bf16x8*)((const char*)As + bb + r * 64 + pc);
        }
        #pragma unroll
        for (int n = 0; n < 2; ++n) {
            int rb = n * 16 + fr;                      // Pt row 0..31
            int pcb = (k0 * 2 + fkb) ^ ((rb & 7) << 4);
            bf_[n] = *(const bf16x8*)((const char*)Bs + rb * 512 + pcb);
        }
        #pragma unroll
        for (int m = 0; m < 2; ++m)
            #pragma unroll
            for (int n = 0; n < 2; ++n)
                a2[m][n] = __builtin_amdgcn_mfma_f32_16x16x32_bf16(af[m], bf_[n], a2[m][n], 0, 0, 0);
    };
    stageA(0, 0);
    __syncthreads();
    int cur = 0;
    #pragma unroll
    for (int k0 = 32; k0 < 256; k0 += 32) {
        stageA(cur ^ 1, k0);
        computeA(cur, k0 - 32);
        __syncthreads();
        cur ^= 1;
    }
    computeA(cur, 224);
    #pragma unroll
    for (int m = 0; m < 2; ++m)
        #pragma unroll
        for (int j = 0; j < 4; ++j) {
            int r = m0 + wave * 32 + m * 16 + orow + j;
            if (fr < 12 && r < M) {
                alpha_src[(size_t)r * AP + fr] = a2[m][0][j];
                alpha_dst[(size_t)r * AP + fr] = a2[m][1][j];
            }
        }
}

// GEMM2: out(f32)[M,256] = x + xcat(bf16) @ WTu^T + bu  (nt residual/out)
__global__ __launch_bounds__(256) void gemm2_mfma(const unsigned short* __restrict__ Ab,
                                                  const unsigned short* __restrict__ Bt,
                                                  const float* __restrict__ bu,
                                                  const float* __restrict__ xres,
                                                  float* __restrict__ C, int M, int MB) {
    __shared__ unsigned short As[8192];
    __shared__ unsigned short Bs[8192];
    const int s = blockIdx.x;
    const int xcd = s & 7;
    const int jj = s >> 3;
    const int n_blk = jj & 1;                          // NB=2
    const int m_blk = (jj >> 1) * 8 + xcd;
    if (m_blk >= MB) return;
    const int m0 = m_blk * 128, n0 = n_blk * 128;
    const int lane = threadIdx.x & 63;
    const int wave = threadIdx.x >> 6;
    const int wr = wave >> 1, wc = wave & 1;
    f32x4 acc[4][4] = {};
    gemm_core32<512>(Ab, Bt, As, Bs, acc, m0, n0, M);
    const int fr = lane & 15;
    const int orow = (lane >> 4) * 4;
    #pragma unroll
    for (int m = 0; m < 4; ++m)
        #pragma unroll
        for (int j = 0; j < 4; ++j) {
            int r = m0 + wr * 64 + m * 16 + orow + j;
            if (r < M) {
                #pragma unroll
                for (int n = 0; n < 4; ++n) {
                    int ccol = n0 + wc * 64 + n * 16 + fr;
                    float xr = __builtin_nontemporal_load(&xres[(size_t)r * CH + ccol]);
                    __builtin_nontemporal_store(acc[m][n][j] + bu[ccol] + xr,
                                                &C[(size_t)r * CH + ccol]);
                }
            }
        }
}

// ---------------------------------------------------------------------------
// CSR build (scan adds +1 self-loop per node; deg holds in-degree only)
// ---------------------------------------------------------------------------
__global__ __launch_bounds__(256) void scan1_kernel(const int* __restrict__ deg, int* __restrict__ pre,
                                                    int* __restrict__ bsum, int n) {
    __shared__ int wsum[4];
    int t = threadIdx.x, lane = t & 63, w = t >> 6;
    int base = blockIdx.x * 1024 + t * 4;
    int v0 = base     < n ? deg[base]     + 1 : 0;
    int v1 = base + 1 < n ? deg[base + 1] + 1 : 0;
    int v2 = base + 2 < n ? deg[base + 2] + 1 : 0;
    int v3 = base + 3 < n ? deg[base + 3] + 1 : 0;
    int s = v0 + v1 + v2 + v3;
    int sc = s;
    #pragma unroll
    for (int o = 1; o < 64; o <<= 1) { int xx = __shfl_up(sc, o); if (lane >= o) sc += xx; }
    if (lane == 63) wsum[w] = sc;
    __syncthreads();
    int wo = 0;
    #pragma unroll
    for (int k = 0; k < 4; ++k) if (k < w) wo += wsum[k];
    int p = wo + sc - s;
    if (base     < n) pre[base]     = p; p += v0;
    if (base + 1 < n) pre[base + 1] = p; p += v1;
    if (base + 2 < n) pre[base + 2] = p; p += v2;
    if (base + 3 < n) pre[base + 3] = p;
    if (t == 255) bsum[blockIdx.x] = wo + sc;
}
// scan3 + csr_init, with scan2 folded in: each thread serially prefixes the
// <=49 raw block sums for its chunk (L2-resident, trivial).
__global__ void scan3_csr_kernel(const int* __restrict__ pre, const int* __restrict__ bsum,
                                 int* __restrict__ offsets, int* __restrict__ cursor,
                                 int* __restrict__ csr, int n, int total) {
    int i = blockIdx.x * 256 + threadIdx.x;
    if (i < n) {
        int chunk = i >> 10;
        int boff = 0;
        for (int k = 0; k < chunk; ++k) boff += bsum[k];
        int off = pre[i] + boff;
        offsets[i] = off;
        cursor[i] = off + 1;
        csr[off] = i;                                  // self-loop slot 0
    }
    if (i == 0) offsets[n] = total;
}
__global__ void scatter_kernel(const int* __restrict__ src, const int* __restrict__ dst,
                               int* __restrict__ cursor, int* __restrict__ csr, int E) {
    int i = blockIdx.x * blockDim.x + threadIdx.x;
    if (i < E) {
        int pos = atomicAdd(&cursor[dst[i]], 1);
        csr[pos] = src[i];
    }
}

// ---------------------------------------------------------------------------
// Aggregation (R9-proven form): ONE wave per node, 8 fp8 ch/lane, single edge
// pass, post-normalized softmax, scalarized control stream, f32x2 accum.
// ---------------------------------------------------------------------------
__global__ void aggregate_kernel(const unsigned char* __restrict__ Hq,
                                 const float* __restrict__ alpha_src,
                                 const float* __restrict__ alpha_dst,
                                 const int* __restrict__ offsets,
                                 const int* __restrict__ csr,
                                 const float* __restrict__ b1, const float* __restrict__ b2,
                                 unsigned short* __restrict__ xcb, int N) {
    int n = __builtin_amdgcn_readfirstlane((int)((blockIdx.x * blockDim.x + threadIdx.x) >> 6));
    int lane = threadIdx.x & 63;
    if (n >= N) return;
    int beg = offsets[n], end = offsets[n + 1];
    int c0 = lane * 8;
    int hid = (lane < 32) ? (lane >> 3) : (4 + ((lane - 32) >> 2));
    float adh = alpha_dst[(size_t)n * AP + hid];

    float ssum = 0.f;
    f32x2 A0 = {0.f, 0.f}, A1 = {0.f, 0.f}, A2 = {0.f, 0.f}, A3 = {0.f, 0.f};

    int i = beg;
    for (; i + 4 <= end; i += 4) {
        int ss[4];
        #pragma unroll
        for (int u = 0; u < 4; ++u) ss[u] = csr[i + u];          // scalar loads (uniform addr)
        float lw[4];
        #pragma unroll
        for (int u = 0; u < 4; ++u) lw[u] = alpha_src[(size_t)ss[u] * AP + hid];
        uint2 hv[4];
        #pragma unroll
        for (int u = 0; u < 4; ++u) hv[u] = *(const uint2*)(Hq + (size_t)ss[u] * CC + c0);
        #pragma unroll
        for (int u = 0; u < 4; ++u) {
            float l = lw[u] + adh;
            l = fmaxf(l, 0.2f * l);                              // leaky relu
            float wv = __expf(l);
            ssum += wv;
            f32x2 wv2; wv2[0] = wv; wv2[1] = wv;
            A0 += __builtin_amdgcn_cvt_pk_f32_fp8(hv[u].x, false) * wv2;
            A1 += __builtin_amdgcn_cvt_pk_f32_fp8(hv[u].x, true)  * wv2;
            A2 += __builtin_amdgcn_cvt_pk_f32_fp8(hv[u].y, false) * wv2;
            A3 += __builtin_amdgcn_cvt_pk_f32_fp8(hv[u].y, true)  * wv2;
        }
    }
    for (; i < end; ++i) {
        int s0 = csr[i];
        float l = alpha_src[(size_t)s0 * AP + hid] + adh;
        uint2 hv0 = *(const uint2*)(Hq + (size_t)s0 * CC + c0);
        l = fmaxf(l, 0.2f * l);
        float wv = __expf(l);
        ssum += wv;
        f32x2 wv2; wv2[0] = wv; wv2[1] = wv;
        A0 += __builtin_amdgcn_cvt_pk_f32_fp8(hv0.x, false) * wv2;
        A1 += __builtin_amdgcn_cvt_pk_f32_fp8(hv0.x, true)  * wv2;
        A2 += __builtin_amdgcn_cvt_pk_f32_fp8(hv0.y, false) * wv2;
        A3 += __builtin_amdgcn_cvt_pk_f32_fp8(hv0.y, true)  * wv2;
    }

    float inv = 1.0f / (ssum + 1e-16f);
    const float* bb = (c0 < 256) ? (b1 + c0) : (b2 + (c0 - 256));
    float4 bb0 = *(const float4*)(bb), bb1 = *(const float4*)(bb + 4);
    float o[8];
    o[0] = A0[0] * inv + bb0.x; o[1] = A0[1] * inv + bb0.y;
    o[2] = A1[0] * inv + bb0.z; o[3] = A1[1] * inv + bb0.w;
    o[4] = A2[0] * inv + bb1.x; o[5] = A2[1] * inv + bb1.y;
    o[6] = A3[0] * inv + bb1.z; o[7] = A3[1] * inv + bb1.w;
    #pragma unroll
    for (int j = 0; j < 8; ++j) o[j] = o[j] > 0.f ? o[j] : expm1f(o[j]);
    unsigned short u[8];
    #pragma unroll
    for (int j = 0; j < 8; ++j) u[j] = f2bf(o[j]);
    i32x4 pk;
    pk[0] = (int)((unsigned)u[0] | ((unsigned)u[1] << 16));
    pk[1] = (int)((unsigned)u[2] | ((unsigned)u[3] << 16));
    pk[2] = (int)((unsigned)u[4] | ((unsigned)u[5] << 16));
    pk[3] = (int)((unsigned)u[6] | ((unsigned)u[7] << 16));
    __builtin_nontemporal_store(pk, (i32x4*)(xcb + (size_t)n * CC + c0));
}

// ---------------------------------------------------------------------------
// Launch (7 dispatches)
// ---------------------------------------------------------------------------
extern "C" void kernel_launch(void* const* d_in, const int* in_sizes, int n_in,
                              void* d_out, int out_size, void* d_ws, size_t ws_size,
                              hipStream_t stream) {
    const float* x     = (const float*)d_in[0];
    const int*   ei    = (const int*)d_in[1];
    const float* gamma = (const float*)d_in[2];
    const float* beta  = (const float*)d_in[3];
    const float* W1    = (const float*)d_in[4];
    const float* as1   = (const float*)d_in[5];
    const float* ad1   = (const float*)d_in[6];
    const float* b1    = (const float*)d_in[7];
    const float* W2    = (const float*)d_in[8];
    const float* as2   = (const float*)d_in[9];
    const float* ad2   = (const float*)d_in[10];
    const float* b2    = (const float*)d_in[11];
    const float* Wu    = (const float*)d_in[12];
    const float* bu    = (const float*)d_in[13];
    float* out = (float*)d_out;

    const int N = in_sizes[0] / CH;
    const int E = in_sizes[1] / 2;
    const int* src = ei;
    const int* dst = ei + E;

    char* w = (char*)d_ws;
    auto alloc = [&](size_t bytes) { char* p = w; w += (bytes + 255) & ~(size_t)255; return p; };
    unsigned char*  Hq  = (unsigned char*)alloc((size_t)N * CC);
    unsigned short* xnb = (unsigned short*)alloc((size_t)N * CH * 2);
    unsigned short* xcb = (unsigned short*)alloc((size_t)N * CC * 2);
    unsigned short* WT1 = (unsigned short*)alloc(512 * 256 * 2);
    unsigned short* WTu = (unsigned short*)alloc(256 * 512 * 2);
    unsigned short* Pt  = (unsigned short*)alloc(32 * 256 * 2);
    float* alpha_src = (float*)alloc((size_t)N * AP * 4);
    float* alpha_dst = (float*)alloc((size_t)N * AP * 4);
    int* deg     = (int*)alloc((size_t)N * 4);
    int* pre     = (int*)alloc((size_t)N * 4);
    int* bsum    = (int*)alloc(64 * 4);
    int* offsets = (int*)alloc(((size_t)N + 1) * 4);
    int* cursor  = (int*)alloc((size_t)N * 4);
    int* csr     = (int*)alloc(((size_t)E + N) * 4);

    const int LNB = (N + 3) / 4;
    const int DEGZ = (N + 255) / 256;
    fused_pre_kernel<<<LNB + 1056 + DEGZ, 256, 0, stream>>>(
        x, gamma, beta, W1, W2, Wu, as1, ad1, as2, ad2,
        xnb, WT1, WTu, Pt, deg, N, LNB);

    const int MB = (N + 127) / 128;
    const int MB8 = ((MB + 7) / 8) * 8;
    const int G1B = MB8 * 4;
    const int HB = (E + 255) / 256;
    gemm1_mfma<<<G1B + MB + HB, 256, 0, stream>>>(xnb, WT1, Pt, Hq, alpha_src, alpha_dst,
                                                  N, MB, G1B, dst, deg, E);

    int nb = (N + 1023) / 1024;
    scan1_kernel<<<nb, 256, 0, stream>>>(deg, pre, bsum, N);
    scan3_csr_kernel<<<(N + 255) / 256, 256, 0, stream>>>(pre, bsum, offsets, cursor, csr, N, E + N);
    scatter_kernel<<<(E + 255) / 256, 256, 0, stream>>>(src, dst, cursor, csr, E);

    aggregate_kernel<<<(N + 3) / 4, 256, 0, stream>>>(Hq, alpha_src, alpha_dst, offsets, csr,
                                                      b1, b2, xcb, N);

    gemm2_mfma<<<MB8 * 2, 256, 0, stream>>>(xcb, WTu, bu, x, out, N, MB);
}

// Round 12
// 190.817 us; speedup vs baseline: 1.0796x; 1.0182x over previous
//
#include <hip/hip_runtime.h>
#include <hip/hip_bf16.h>
#include <math.h>

constexpr int CH = 256;       // input channels
constexpr int CC = 512;       // concat width
constexpr int AP = 16;        // padded alpha row stride (12 heads used)

typedef __bf16 bf16x8 __attribute__((ext_vector_type(8)));
typedef float  f32x4  __attribute__((ext_vector_type(4)));
typedef float  f32x2  __attribute__((ext_vector_type(2)));
typedef int    i32x4  __attribute__((ext_vector_type(4)));
typedef __attribute__((address_space(3))) void lds_void;
typedef __attribute__((address_space(1))) void glb_void;

__device__ inline unsigned short f2bf(float f) {
    union { float f; unsigned u; } v; v.f = f;
    unsigned r = v.u + 0x7FFFu + ((v.u >> 16) & 1u);
    return (unsigned short)(r >> 16);
}
// storage->logical channel permutation (within each 32-ch group):
// storage s: logical = (s & ~31) + 16*(s&1) + ((s&31)>>1)
__device__ __host__ inline int perm_s2l(int s) {
    return (s & ~31) + 16 * (s & 1) + ((s & 31) >> 1);
}

// ---------------------------------------------------------------------------
// Fused pre-pass: LN(->bf16) + weight transpose/convert + Pt=(W·a) + bperm +
// deg zero.  blocks: [0,LNB) LN | +512 WT1 | +512 WTu | +32 Pt | +2 bperm | +DEGZ
// ---------------------------------------------------------------------------
__global__ void fused_pre_kernel(const float* __restrict__ x, const float* __restrict__ gamma,
                                 const float* __restrict__ beta,
                                 const float* __restrict__ W1, const float* __restrict__ W2,
                                 const float* __restrict__ Wu,
                                 const float* __restrict__ as1, const float* __restrict__ ad1,
                                 const float* __restrict__ as2, const float* __restrict__ ad2,
                                 const float* __restrict__ b1, const float* __restrict__ b2,
                                 unsigned short* __restrict__ xnb,
                                 unsigned short* __restrict__ WT1, unsigned short* __restrict__ WTu,
                                 unsigned short* __restrict__ Pt, float* __restrict__ bperm,
                                 int* __restrict__ deg,
                                 int N, int LNB) {
    int b = blockIdx.x;
    int t = threadIdx.x;
    if (b < LNB) {
        int wid = b * 4 + (t >> 6);
        int lane = t & 63;
        if (wid >= N) return;
        const float4 v = *(const float4*)(x + (size_t)wid * CH + lane * 4);
        float s = v.x + v.y + v.z + v.w;
        float sq = v.x * v.x + v.y * v.y + v.z * v.z + v.w * v.w;
        #pragma unroll
        for (int o = 32; o; o >>= 1) { s += __shfl_xor(s, o); sq += __shfl_xor(sq, o); }
        float mu = s * (1.0f / CH);
        float var = sq * (1.0f / CH) - mu * mu;
        float rs = rsqrtf(var + 1e-5f);
        float4 g = *(const float4*)(gamma + lane * 4);
        float4 bb = *(const float4*)(beta + lane * 4);
        unsigned short o0 = f2bf((v.x - mu) * rs * g.x + bb.x);
        unsigned short o1 = f2bf((v.y - mu) * rs * g.y + bb.y);
        unsigned short o2 = f2bf((v.z - mu) * rs * g.z + bb.z);
        unsigned short o3 = f2bf((v.w - mu) * rs * g.w + bb.w);
        uint2 pk;
        pk.x = (unsigned)o0 | ((unsigned)o1 << 16);
        pk.y = (unsigned)o2 | ((unsigned)o3 << 16);
        *(uint2*)(xnb + (size_t)wid * CH + lane * 4) = pk;
    } else if (b < LNB + 512) {
        int idx = (b - LNB) * 256 + t;              // 512*256
        int n = idx >> 8, k = idx & 255;
        float v = (n < 256) ? W1[(size_t)k * 256 + n] : W2[(size_t)k * 256 + (n - 256)];
        WT1[idx] = f2bf(v);
    } else if (b < LNB + 1024) {
        int idx = (b - LNB - 512) * 256 + t;        // 256*512
        int n = idx >> 9, ks = idx & 511;
        int kl = perm_s2l(ks);                      // permuted concat channel
        WTu[idx] = f2bf(Wu[(size_t)kl * 256 + n]);
    } else if (b < LNB + 1056) {
        // Pt[32][256]: row n = α-projection col; cols 0..11 src, 16..27 dst
        int n = b - LNB - 1024;                     // 0..31
        int k = t;                                  // 0..255
        float a = 0.f;
        if (n < 4) {
            for (int c = 0; c < 64; ++c) a += W1[(size_t)k * 256 + n * 64 + c] * as1[n * 64 + c];
        } else if (n < 12) {
            for (int c = 0; c < 32; ++c) a += W2[(size_t)k * 256 + (n - 4) * 32 + c] * as2[(n - 4) * 32 + c];
        } else if (n >= 16 && n < 20) {
            for (int c = 0; c < 64; ++c) a += W1[(size_t)k * 256 + (n - 16) * 64 + c] * ad1[(n - 16) * 64 + c];
        } else if (n >= 20 && n < 28) {
            for (int c = 0; c < 32; ++c) a += W2[(size_t)k * 256 + (n - 20) * 32 + c] * ad2[(n - 20) * 32 + c];
        }
        Pt[n * 256 + k] = f2bf(a);
    } else if (b < LNB + 1058) {
        int ks = (b - LNB - 1056) * 256 + t;        // 0..511
        int kl = perm_s2l(ks);
        bperm[ks] = (kl < 256) ? b1[kl] : b2[kl - 256];
    } else {
        int i = (b - LNB - 1058) * 256 + t;
        if (i < N) deg[i] = 0;                      // zero for histogram
    }
}

// ---------------------------------------------------------------------------
// bf16 MFMA GEMM core, 128x128 tile, BK=32, 4 waves, double-buffered LDS.
// ---------------------------------------------------------------------------
template<int K>
__device__ inline void gemm_core32(const unsigned short* __restrict__ Ab,
                                   const unsigned short* __restrict__ Bt,
                                   unsigned short* As, unsigned short* Bs,   // each [2][128*32]
                                   f32x4 acc[4][4], int m0, int n0, int M) {
    const int t = threadIdx.x;
    const int lane = t & 63;
    const int wave = t >> 6;
    const int wr = wave >> 1, wc = wave & 1;
    const int rowc = lane >> 2;                        // row within 16-row chunk
    const int eslot = lane & 3;                        // 16B slot within 64B row
    const int fr = lane & 15;
    const int fkb = (lane >> 4) << 4;                  // logical colbyte

    auto stage = [&](int buf, int k0) {
        #pragma unroll
        for (int c = 0; c < 2; ++c) {
            int chunk = wave * 2 + c;                  // 0..7 (16 rows each)
            int row = chunk * 16 + rowc;               // 0..127
            int se = ((eslot ^ (row & 3)) << 3);       // inverse-swizzled elem col
            int gra = m0 + row; if (gra >= M) gra = M - 1;
            __builtin_amdgcn_global_load_lds((const glb_void*)(Ab + (size_t)gra * K + k0 + se),
                                             (lds_void*)&As[buf * 4096 + chunk * 512], 16, 0, 0);
            __builtin_amdgcn_global_load_lds((const glb_void*)(Bt + (size_t)(n0 + row) * K + k0 + se),
                                             (lds_void*)&Bs[buf * 4096 + chunk * 512], 16, 0, 0);
        }
    };
    auto compute = [&](int buf) {
        const int bb = buf * 8192;                     // byte offset
        bf16x8 af[4], bfr[4];
        #pragma unroll
        for (int m = 0; m < 4; ++m) {
            int r = wr * 64 + m * 16 + fr;
            int pc = fkb ^ ((r & 3) << 4);
            af[m] = *(const bf16x8*)((const char*)As + bb + r * 64 + pc);
        }
        #pragma unroll
        for (int n = 0; n < 4; ++n) {
            int r = wc * 64 + n * 16 + fr;
            int pc = fkb ^ ((r & 3) << 4);
            bfr[n] = *(const bf16x8*)((const char*)Bs + bb + r * 64 + pc);
        }
        #pragma unroll
        for (int m = 0; m < 4; ++m)
            #pragma unroll
            for (int n = 0; n < 4; ++n)
                acc[m][n] = __builtin_amdgcn_mfma_f32_16x16x32_bf16(af[m], bfr[n], acc[m][n], 0, 0, 0);
    };

    stage(0, 0);
    __syncthreads();
    int cur = 0;
    #pragma unroll
    for (int k0 = 32; k0 < K; k0 += 32) {
        stage(cur ^ 1, k0);     // issue next-tile loads
        compute(cur);           // MFMA on current tile
        __syncthreads();
        cur ^= 1;
    }
    compute(cur);
}

// GEMM1 grid: [0,G1B) main h-GEMM | [G1B,G1B+MB) alpha panel | rest histogram
// Hq stored PERMUTED: within each 32-ch group, storage = 2*fr + n_pair.
__global__ __launch_bounds__(256) void gemm1_mfma(
    const unsigned short* __restrict__ Ab, const unsigned short* __restrict__ Bt,
    const unsigned short* __restrict__ Pt,
    unsigned char* __restrict__ Hq,
    float* __restrict__ alpha_src, float* __restrict__ alpha_dst, int M, int MB, int G1B,
    const int* __restrict__ dstE, int* __restrict__ deg, int E) {
    __shared__ unsigned short As[8192];                // 2 bufs x 128x32
    __shared__ unsigned short Bs[8192];                // main: 2 bufs; alpha: Pt[32][256]
    const int s = blockIdx.x;
    if (s >= G1B + MB) {                               // fused histogram blocks
        int i = (s - G1B - MB) * 256 + threadIdx.x;
        if (i < E) atomicAdd(&deg[dstE[i]], 1);
        return;
    }
    const int lane = threadIdx.x & 63;
    const int wave = threadIdx.x >> 6;
    const int fr = lane & 15;
    const int fkb = (lane >> 4) << 4;
    const int orow = (lane >> 4) * 4;

    if (s < G1B) {
        const int xcd = s & 7;
        const int jj = s >> 3;
        const int n_blk = jj & 3;                      // NB=4
        const int m_blk = (jj >> 2) * 8 + xcd;
        if (m_blk >= MB) return;
        const int m0 = m_blk * 128, n0 = n_blk * 128;
        const int wr = wave >> 1, wc = wave & 1;
        f32x4 acc[4][4] = {};
        gemm_core32<256>(Ab, Bt, As, Bs, acc, m0, n0, M);
        // fp8 e4m3 PAIRED stores: (n=2p, n=2p+1) -> adjacent bytes at
        // storage col n0 + wc*64 + p*32 + 2*fr
        #pragma unroll
        for (int m = 0; m < 4; ++m)
            #pragma unroll
            for (int j = 0; j < 4; ++j) {
                int r = m0 + wr * 64 + m * 16 + orow + j;
                if (r < M) {
                    #pragma unroll
                    for (int p = 0; p < 2; ++p) {
                        int cst = n0 + wc * 64 + p * 32 + fr * 2;
                        unsigned q = (unsigned)__builtin_amdgcn_cvt_pk_fp8_f32(
                            acc[m][2 * p][j], acc[m][2 * p + 1][j], 0, false);
                        *(unsigned short*)(Hq + (size_t)r * CC + cst) = (unsigned short)q;
                    }
                }
            }
        return;
    }
    // ---- alpha panel block: 128 rows x 32 cols, K=256, Pt resident in LDS ----
    const int m_blk = s - G1B;
    if (m_blk >= MB) return;
    const int m0 = m_blk * 128;
    {
        int rr_in = lane >> 5;                         // 0..1
        int e32 = lane & 31;                           // 16B slot within 512B row
        #pragma unroll
        for (int c = 0; c < 4; ++c) {
            int chunk = wave * 4 + c;                  // 0..15
            int rr = chunk * 2 + rr_in;                // 0..31
            const unsigned short* g = Pt + rr * 256 + ((e32 ^ (rr & 7)) << 3);
            __builtin_amdgcn_global_load_lds((const glb_void*)g,
                                             (lds_void*)&Bs[chunk * 512], 16, 0, 0);
        }
    }
    const int rowc = lane >> 2, eslot = lane & 3;
    auto stageA = [&](int buf, int k0) {
        #pragma unroll
        for (int c = 0; c < 2; ++c) {
            int chunk = wave * 2 + c;
            int row = chunk * 16 + rowc;
            int gra = m0 + row; if (gra >= M) gra = M - 1;
            const unsigned short* g = Ab + (size_t)gra * 256 + k0 + ((eslot ^ (row & 3)) << 3);
            __builtin_amdgcn_global_load_lds((const glb_void*)g,
                                             (lds_void*)&As[buf * 4096 + chunk * 512], 16, 0, 0);
        }
    };
    f32x4 a2[2][2] = {};
    auto computeA = [&](int buf, int k0) {
        const int bb = buf * 8192;
        bf16x8 af[2], bf_[2];
        #pragma unroll
        for (int m = 0; m < 2; ++m) {
            int r = wave * 32 + m * 16 + fr;
            int pc = fkb ^ ((r & 3) << 4);
            af[m] = *(const bf16x8*)((const char*)As + bb + r * 64 + pc);
        }
        #pragma unroll
        for (int n = 0; n < 2; ++n) {
            int rb = n * 16 + fr;                      // Pt row 0..31
            int pcb = (k0 * 2 + fkb) ^ ((rb & 7) << 4);
            bf_[n] = *(const bf16x8*)((const char*)Bs + rb * 512 + pcb);
        }
        #pragma unroll
        for (int m = 0; m < 2; ++m)
            #pragma unroll
            for (int n = 0; n < 2; ++n)
                a2[m][n] = __builtin_amdgcn_mfma_f32_16x16x32_bf16(af[m], bf_[n], a2[m][n], 0, 0, 0);
    };
    stageA(0, 0);
    __syncthreads();
    int cur = 0;
    #pragma unroll
    for (int k0 = 32; k0 < 256; k0 += 32) {
        stageA(cur ^ 1, k0);
        computeA(cur, k0 - 32);
        __syncthreads();
        cur ^= 1;
    }
    computeA(cur, 224);
    #pragma unroll
    for (int m = 0; m < 2; ++m)
        #pragma unroll
        for (int j = 0; j < 4; ++j) {
            int r = m0 + wave * 32 + m * 16 + orow + j;
            if (fr < 12 && r < M) {
                alpha_src[(size_t)r * AP + fr] = a2[m][0][j];
                alpha_dst[(size_t)r * AP + fr] = a2[m][1][j];
            }
        }
}

// GEMM2: out(f32)[M,256] = x + xcat(bf16,permuted) @ WTu^T + bu (WTu k-permuted)
__global__ __launch_bounds__(256) void gemm2_mfma(const unsigned short* __restrict__ Ab,
                                                  const unsigned short* __restrict__ Bt,
                                                  const float* __restrict__ bu,
                                                  const float* __restrict__ xres,
                                                  float* __restrict__ C, int M, int MB) {
    __shared__ unsigned short As[8192];
    __shared__ unsigned short Bs[8192];
    const int s = blockIdx.x;
    const int xcd = s & 7;
    const int jj = s >> 3;
    const int n_blk = jj & 1;                          // NB=2
    const int m_blk = (jj >> 1) * 8 + xcd;
    if (m_blk >= MB) return;
    const int m0 = m_blk * 128, n0 = n_blk * 128;
    const int lane = threadIdx.x & 63;
    const int wave = threadIdx.x >> 6;
    const int wr = wave >> 1, wc = wave & 1;
    f32x4 acc[4][4] = {};
    gemm_core32<512>(Ab, Bt, As, Bs, acc, m0, n0, M);
    const int fr = lane & 15;
    const int orow = (lane >> 4) * 4;
    #pragma unroll
    for (int m = 0; m < 4; ++m)
        #pragma unroll
        for (int j = 0; j < 4; ++j) {
            int r = m0 + wr * 64 + m * 16 + orow + j;
            if (r < M) {
                #pragma unroll
                for (int n = 0; n < 4; ++n) {
                    int ccol = n0 + wc * 64 + n * 16 + fr;
                    float xr = __builtin_nontemporal_load(&xres[(size_t)r * CH + ccol]);
                    __builtin_nontemporal_store(acc[m][n][j] + bu[ccol] + xr,
                                                &C[(size_t)r * CH + ccol]);
                }
            }
        }
}

// ---------------------------------------------------------------------------
// CSR build (scan adds +1 self-loop per node; deg holds in-degree only)
// ---------------------------------------------------------------------------
__global__ __launch_bounds__(256) void scan1_kernel(const int* __restrict__ deg, int* __restrict__ pre,
                                                    int* __restrict__ bsum, int n) {
    __shared__ int wsum[4];
    int t = threadIdx.x, lane = t & 63, w = t >> 6;
    int base = blockIdx.x * 1024 + t * 4;
    int v0 = base     < n ? deg[base]     + 1 : 0;
    int v1 = base + 1 < n ? deg[base + 1] + 1 : 0;
    int v2 = base + 2 < n ? deg[base + 2] + 1 : 0;
    int v3 = base + 3 < n ? deg[base + 3] + 1 : 0;
    int s = v0 + v1 + v2 + v3;
    int sc = s;
    #pragma unroll
    for (int o = 1; o < 64; o <<= 1) { int xx = __shfl_up(sc, o); if (lane >= o) sc += xx; }
    if (lane == 63) wsum[w] = sc;
    __syncthreads();
    int wo = 0;
    #pragma unroll
    for (int k = 0; k < 4; ++k) if (k < w) wo += wsum[k];
    int p = wo + sc - s;
    if (base     < n) pre[base]     = p; p += v0;
    if (base + 1 < n) pre[base + 1] = p; p += v1;
    if (base + 2 < n) pre[base + 2] = p; p += v2;
    if (base + 3 < n) pre[base + 3] = p;
    if (t == 255) bsum[blockIdx.x] = wo + sc;
}
__global__ void scan3_csr_kernel(const int* __restrict__ pre, const int* __restrict__ bsum,
                                 int* __restrict__ offsets, int* __restrict__ cursor,
                                 int* __restrict__ csr, int n, int total) {
    int i = blockIdx.x * 256 + threadIdx.x;
    if (i < n) {
        int chunk = i >> 10;
        int boff = 0;
        for (int k = 0; k < chunk; ++k) boff += bsum[k];
        int off = pre[i] + boff;
        offsets[i] = off;
        cursor[i] = off + 1;
        csr[off] = i;                                  // self-loop slot 0
    }
    if (i == 0) offsets[n] = total;
}
__global__ void scatter_kernel(const int* __restrict__ src, const int* __restrict__ dst,
                               int* __restrict__ cursor, int* __restrict__ csr, int E) {
    int i = blockIdx.x * blockDim.x + threadIdx.x;
    if (i < E) {
        int pos = atomicAdd(&cursor[dst[i]], 1);
        csr[pos] = src[i];
    }
}

// ---------------------------------------------------------------------------
// Aggregation (R9-proven form): ONE wave per node, 8 fp8 ch/lane, single edge
// pass, post-normalized softmax, scalarized control stream, f32x2 accum.
// Channels storage-permuted; bias via bperm (contiguous).
// ---------------------------------------------------------------------------
__global__ void aggregate_kernel(const unsigned char* __restrict__ Hq,
                                 const float* __restrict__ alpha_src,
                                 const float* __restrict__ alpha_dst,
                                 const int* __restrict__ offsets,
                                 const int* __restrict__ csr,
                                 const float* __restrict__ bperm,
                                 unsigned short* __restrict__ xcb, int N) {
    int n = __builtin_amdgcn_readfirstlane((int)((blockIdx.x * blockDim.x + threadIdx.x) >> 6));
    int lane = threadIdx.x & 63;
    if (n >= N) return;
    int beg = offsets[n], end = offsets[n + 1];
    int c0 = lane * 8;
    int hid = (lane < 32) ? (lane >> 3) : (4 + ((lane - 32) >> 2));
    float adh = alpha_dst[(size_t)n * AP + hid];

    float ssum = 0.f;
    f32x2 A0 = {0.f, 0.f}, A1 = {0.f, 0.f}, A2 = {0.f, 0.f}, A3 = {0.f, 0.f};

    int i = beg;
    for (; i + 4 <= end; i += 4) {
        int ss[4];
        #pragma unroll
        for (int u = 0; u < 4; ++u) ss[u] = csr[i + u];          // scalar loads (uniform addr)
        float lw[4];
        #pragma unroll
        for (int u = 0; u < 4; ++u) lw[u] = alpha_src[(size_t)ss[u] * AP + hid];
        uint2 hv[4];
        #pragma unroll
        for (int u = 0; u < 4; ++u) hv[u] = *(const uint2*)(Hq + (size_t)ss[u] * CC + c0);
        #pragma unroll
        for (int u = 0; u < 4; ++u) {
            float l = lw[u] + adh;
            l = fmaxf(l, 0.2f * l);                              // leaky relu
            float wv = __expf(l);
            ssum += wv;
            f32x2 wv2; wv2[0] = wv; wv2[1] = wv;
            A0 += __builtin_amdgcn_cvt_pk_f32_fp8(hv[u].x, false) * wv2;
            A1 += __builtin_amdgcn_cvt_pk_f32_fp8(hv[u].x, true)  * wv2;
            A2 += __builtin_amdgcn_cvt_pk_f32_fp8(hv[u].y, false) * wv2;
            A3 += __builtin_amdgcn_cvt_pk_f32_fp8(hv[u].y, true)  * wv2;
        }
    }
    for (; i < end; ++i) {
        int s0 = csr[i];
        float l = alpha_src[(size_t)s0 * AP + hid] + adh;
        uint2 hv0 = *(const uint2*)(Hq + (size_t)s0 * CC + c0);
        l = fmaxf(l, 0.2f * l);
        float wv = __expf(l);
        ssum += wv;
        f32x2 wv2; wv2[0] = wv; wv2[1] = wv;
        A0 += __builtin_amdgcn_cvt_pk_f32_fp8(hv0.x, false) * wv2;
        A1 += __builtin_amdgcn_cvt_pk_f32_fp8(hv0.x, true)  * wv2;
        A2 += __builtin_amdgcn_cvt_pk_f32_fp8(hv0.y, false) * wv2;
        A3 += __builtin_amdgcn_cvt_pk_f32_fp8(hv0.y, true)  * wv2;
    }

    float inv = 1.0f / (ssum + 1e-16f);
    float4 bb0 = *(const float4*)(bperm + c0);
    float4 bb1 = *(const float4*)(bperm + c0 + 4);
    float o[8];
    o[0] = A0[0] * inv + bb0.x; o[1] = A0[1] * inv + bb0.y;
    o[2] = A1[0] * inv + bb0.z; o[3] = A1[1] * inv + bb0.w;
    o[4] = A2[0] * inv + bb1.x; o[5] = A2[1] * inv + bb1.y;
    o[6] = A3[0] * inv + bb1.z; o[7] = A3[1] * inv + bb1.w;
    #pragma unroll
    for (int j = 0; j < 8; ++j) o[j] = o[j] > 0.f ? o[j] : expm1f(o[j]);
    unsigned short u[8];
    #pragma unroll
    for (int j = 0; j < 8; ++j) u[j] = f2bf(o[j]);
    i32x4 pk;
    pk[0] = (int)((unsigned)u[0] | ((unsigned)u[1] << 16));
    pk[1] = (int)((unsigned)u[2] | ((unsigned)u[3] << 16));
    pk[2] = (int)((unsigned)u[4] | ((unsigned)u[5] << 16));
    pk[3] = (int)((unsigned)u[6] | ((unsigned)u[7] << 16));
    __builtin_nontemporal_store(pk, (i32x4*)(xcb + (size_t)n * CC + c0));
}

// ---------------------------------------------------------------------------
// Launch (7 dispatches)
// ---------------------------------------------------------------------------
extern "C" void kernel_launch(void* const* d_in, const int* in_sizes, int n_in,
                              void* d_out, int out_size, void* d_ws, size_t ws_size,
                              hipStream_t stream) {
    const float* x     = (const float*)d_in[0];
    const int*   ei    = (const int*)d_in[1];
    const float* gamma = (const float*)d_in[2];
    const float* beta  = (const float*)d_in[3];
    const float* W1    = (const float*)d_in[4];
    const float* as1   = (const float*)d_in[5];
    const float* ad1   = (const float*)d_in[6];
    const float* b1    = (const float*)d_in[7];
    const float* W2    = (const float*)d_in[8];
    const float* as2   = (const float*)d_in[9];
    const float* ad2   = (const float*)d_in[10];
    const float* b2    = (const float*)d_in[11];
    const float* Wu    = (const float*)d_in[12];
    const float* bu    = (const float*)d_in[13];
    float* out = (float*)d_out;

    const int N = in_sizes[0] / CH;
    const int E = in_sizes[1] / 2;
    const int* src = ei;
    const int* dst = ei + E;

    char* w = (char*)d_ws;
    auto alloc = [&](size_t bytes) { char* p = w; w += (bytes + 255) & ~(size_t)255; return p; };
    unsigned char*  Hq  = (unsigned char*)alloc((size_t)N * CC);
    unsigned short* xnb = (unsigned short*)alloc((size_t)N * CH * 2);
    unsigned short* xcb = (unsigned short*)alloc((size_t)N * CC * 2);
    unsigned short* WT1 = (unsigned short*)alloc(512 * 256 * 2);
    unsigned short* WTu = (unsigned short*)alloc(256 * 512 * 2);
    unsigned short* Pt  = (unsigned short*)alloc(32 * 256 * 2);
    float* bperm = (float*)alloc(512 * 4);
    float* alpha_src = (float*)alloc((size_t)N * AP * 4);
    float* alpha_dst = (float*)alloc((size_t)N * AP * 4);
    int* deg     = (int*)alloc((size_t)N * 4);
    int* pre     = (int*)alloc((size_t)N * 4);
    int* bsum    = (int*)alloc(64 * 4);
    int* offsets = (int*)alloc(((size_t)N + 1) * 4);
    int* cursor  = (int*)alloc((size_t)N * 4);
    int* csr     = (int*)alloc(((size_t)E + N) * 4);

    const int LNB = (N + 3) / 4;
    const int DEGZ = (N + 255) / 256;
    fused_pre_kernel<<<LNB + 1058 + DEGZ, 256, 0, stream>>>(
        x, gamma, beta, W1, W2, Wu, as1, ad1, as2, ad2, b1, b2,
        xnb, WT1, WTu, Pt, bperm, deg, N, LNB);

    const int MB = (N + 127) / 128;
    const int MB8 = ((MB + 7) / 8) * 8;
    const int G1B = MB8 * 4;
    const int HB = (E + 255) / 256;
    gemm1_mfma<<<G1B + MB + HB, 256, 0, stream>>>(xnb, WT1, Pt, Hq, alpha_src, alpha_dst,
                                                  N, MB, G1B, dst, deg, E);

    int nb = (N + 1023) / 1024;
    scan1_kernel<<<nb, 256, 0, stream>>>(deg, pre, bsum, N);
    scan3_csr_kernel<<<(N + 255) / 256, 256, 0, stream>>>(pre, bsum, offsets, cursor, csr, N, E + N);
    scatter_kernel<<<(E + 255) / 256, 256, 0, stream>>>(src, dst, cursor, csr, E);

    aggregate_kernel<<<(N + 3) / 4, 256, 0, stream>>>(Hq, alpha_src, alpha_dst, offsets, csr,
                                                      bperm, xcb, N);

    gemm2_mfma<<<MB8 * 2, 256, 0, stream>>>(xcb, WTu, bu, x, out, N, MB);
}